// Round 21
// baseline (15.928 us; speedup 1.0000x reference)
//
#include <hip/hip_runtime.h>

// Dihedral2Coord — R20 (1-wave blocks, quat-only W64 DPP scan, E=S⊗conj(D),
// 2-stride translation chains, fully-coalesced tail via LDS bounce) with
// staging via gfx950 global_load_lds (width=16): direct global->LDS DMA,
// per-lane global src + wave-uniform LDS base (+lane*16 in HW). Removes the
// global->VGPR->ds_write round trip and ~28 live VGPRs of staged data.

#define NK 128
#define NM 512
#define NMOL 4096
#define TPB 64       // ONE wave per block, one molecule per block
#define TAIL_F4 285  // f4 indices 99..383 (atoms 132..511)

struct Q4 { float w, x, y, z; };

__device__ __forceinline__ Q4 qmul(const Q4& a, const Q4& b) {
    Q4 r;
    r.w = a.w*b.w - a.x*b.x - a.y*b.y - a.z*b.z;
    r.x = a.w*b.x + a.x*b.w + a.y*b.z - a.z*b.y;
    r.y = a.w*b.y - a.x*b.z + a.y*b.w + a.z*b.x;
    r.z = a.w*b.z + a.x*b.y - a.y*b.x + a.z*b.w;
    return r;
}

__device__ __forceinline__ void qrotv(const Q4& q, float vx, float vy, float vz,
                                      float& ox, float& oy, float& oz) {
    const float ux = q.y*vz - q.z*vy + q.w*vx;
    const float uy = q.z*vx - q.x*vz + q.w*vy;
    const float uz = q.x*vy - q.y*vx + q.w*vz;
    ox = vx + 2.f*(q.y*uz - q.z*uy);
    oy = vy + 2.f*(q.z*ux - q.x*uz);
    oz = vz + 2.f*(q.x*uy - q.y*ux);
}

// DPP: ROW_SHR:N = 0x110+N ; ROW_BCAST15 = 0x142 ; ROW_BCAST31 = 0x143.
template <int CTRL, int RMASK>
__device__ __forceinline__ float dpp_mov(float x) {
    return __int_as_float(__builtin_amdgcn_update_dpp(
        0, __float_as_int(x), CTRL, RMASK, 0xF, true));
}

// Direct global->LDS, 16B per lane. gsrc is PER-LANE; lds base is
// WAVE-UNIFORM (HW adds lane*16). Inactive lanes are skipped.
__device__ __forceinline__ void gload_lds16(const void* gsrc, void* lds) {
    __builtin_amdgcn_global_load_lds(
        (const __attribute__((address_space(1))) unsigned int*)gsrc,
        (__attribute__((address_space(3))) unsigned int*)lds, 16, 0, 0);
}

// Step-quat for step 2l+j (validated sphi/cphi formula, R10-R20; quat only)
#define BUILD_Q(j, OUT) do {                                                  \
    const float cxx = ny[(j)+1]*nz[(j)] - nz[(j)+1]*ny[(j)];                  \
    const float cxy = nz[(j)+1]*nx[(j)] - nx[(j)+1]*nz[(j)];                  \
    const float cxz = nx[(j)+1]*ny[(j)] - ny[(j)+1]*nx[(j)];                  \
    const float g   = cxx*vx[(j)+1] + cxy*vy[(j)+1] + cxz*vz[(j)+1];          \
    const float dnn = nx[(j)]*nx[(j)+1] + ny[(j)]*ny[(j)+1] + nz[(j)]*nz[(j)+1]; \
    const float r12 = rsqrtf(fmaxf(Ln[(j)]*Ln[(j)+1], 1e-30f));               \
    const float ira = rsqrtf(fmaxf(Lv[(j)+1], 1e-24f));                       \
    const float cphi = dnn*r12, sphi = g*r12*ira;                             \
    const float sth = __sinf(th[(j)]), cth = __cosf(th[(j)]);                 \
    const float c = cth*cphi - sth*sphi, s = sth*cphi + cth*sphi;             \
    const float hc = sqrtf(fmaxf(0.f, 0.5f*(1.f + c)));                       \
    const float hs = copysignf(sqrtf(fmaxf(0.f, 0.5f*(1.f - c))), s);         \
    const float hsa = hs*ira;                                                 \
    OUT.w = hc; OUT.x = vx[(j)+1]*hsa; OUT.y = vy[(j)+1]*hsa; OUT.z = vz[(j)+1]*hsa; \
} while (0)

__global__ __launch_bounds__(TPB) void dihedral_w64_gld_kernel(
    const float* __restrict__ theta,  // (NMOL, NK)
    const float* __restrict__ pos0,   // (NMOL, NM, 3)
    float* __restrict__ out)          // (NMOL, NM, 3)
{
    const int lane = threadIdx.x;
    const int mol  = blockIdx.x;

    const float4* __restrict__ pb4 = (const float4*)(pos0 + (size_t)mol * (NM*3));
    float4*       __restrict__ ob4 = (float4*)(out  + (size_t)mol * (NM*3));

    __shared__ __align__(16) float sa[400];          // pos0 atoms 0..131
    __shared__ __align__(16) float sout[400];        // final atoms 0..131
    __shared__ __align__(16) float st[TAIL_F4 * 4];  // tail f4s (atoms 132..511)
    float4* sa4 = (float4*)sa;
    float4* st4 = (float4*)st;

    // ---- theta (register) + ALL staging as direct global->LDS DMA ----
    const float2 th2 = ((const float2*)(theta + (size_t)mol * NK))[lane];
    gload_lds16(pb4 + lane, sa4);                                    // head 0..63
    if (lane < 35) gload_lds16(pb4 + 64 + lane, sa4 + 64);           // head 64..98
    gload_lds16(pb4 +  99 + lane, st4);                              // tail rows
    gload_lds16(pb4 + 163 + lane, st4 + 64);
    gload_lds16(pb4 + 227 + lane, st4 + 128);
    gload_lds16(pb4 + 291 + lane, st4 + 192);
    if (lane < TAIL_F4 - 256) gload_lds16(pb4 + 355 + lane, st4 + 256);

    // drain DMA before touching LDS (same-wave; no barrier needed)
    asm volatile("s_waitcnt vmcnt(0)" ::: "memory");
    __builtin_amdgcn_sched_barrier(0);

    // lane l: atoms 2l..2l+4 (15 floats)
    float A[16];
    {
        const float2* ap2 = (const float2*)&sa[lane * 6];
        #pragma unroll
        for (int i = 0; i < 7; ++i) { const float2 v = ap2[i]; A[2*i] = v.x; A[2*i+1] = v.y; }
        A[14] = sa[lane * 6 + 14];
    }

    // bonds / normals for the 2 steps
    float vx[4], vy[4], vz[4];
    #pragma unroll
    for (int i = 0; i < 4; ++i) {
        vx[i] = A[3*i+3] - A[3*i];
        vy[i] = A[3*i+4] - A[3*i+1];
        vz[i] = A[3*i+5] - A[3*i+2];
    }
    float nx[3], ny[3], nz[3], Ln[3];
    #pragma unroll
    for (int i = 0; i < 3; ++i) {
        nx[i] = vy[i]*vz[i+1] - vz[i]*vy[i+1];
        ny[i] = vz[i]*vx[i+1] - vx[i]*vz[i+1];
        nz[i] = vx[i]*vy[i+1] - vy[i]*vx[i+1];
        Ln[i] = nx[i]*nx[i] + ny[i]*ny[i] + nz[i]*nz[i];
    }
    float Lv[3];
    #pragma unroll
    for (int i = 1; i < 3; ++i) Lv[i] = vx[i]*vx[i] + vy[i]*vy[i] + vz[i]*vz[i];
    const float th[2] = {th2.x, th2.y};

    // ---- build 2 step quats; D = q0⊗q1 ----
    Q4 q0, q1;
    BUILD_Q(0, q0); BUILD_Q(1, q1);
    const Q4 D = qmul(q0, q1);
    Q4 S = D;

    // ---- 6-round W64 inclusive quat scan via DPP ----
    const int rowi = lane & 15;
    #define QSCAN_ROUND(CTRL, COND)                                          \
    do {                                                                     \
        Q4 Qp;                                                               \
        Qp.w = dpp_mov<CTRL, 0xF>(S.w); Qp.x = dpp_mov<CTRL, 0xF>(S.x);      \
        Qp.y = dpp_mov<CTRL, 0xF>(S.y); Qp.z = dpp_mov<CTRL, 0xF>(S.z);      \
        if (COND) S = qmul(Qp, S);                                           \
    } while (0)
    QSCAN_ROUND(0x111, rowi >= 1);
    QSCAN_ROUND(0x112, rowi >= 2);
    QSCAN_ROUND(0x114, rowi >= 4);
    QSCAN_ROUND(0x118, rowi >= 8);
    QSCAN_ROUND(0x142, (lane & 16) != 0);   // rows 1,3: prepend lower-row total
    QSCAN_ROUND(0x143, (lane & 32) != 0);   // rows 2,3: prepend rows0-1 total
    #undef QSCAN_ROUND

    // exclusive prefix: E = S ⊗ conj(D)  (unit quats; lane0 -> identity)
    Q4 Dc; Dc.w = D.w; Dc.x = -D.x; Dc.y = -D.y; Dc.z = -D.z;
    const Q4 E  = qmul(S, Dc);
    const Q4 Pe = qmul(E, q0);          // R(P_{2l});  R(P_{2l+1}) = S

    // ---- d = R(P_k)·(pos0[k+3]-pos0[k+1]) ----
    float dex, dey, dez, dox, doy, doz;
    qrotv(Pe, A[9]-A[3],  A[10]-A[4], A[11]-A[5], dex, dey, dez);
    qrotv(S,  A[12]-A[6], A[13]-A[7], A[14]-A[8], dox, doy, doz);

    // ---- two float3 inclusive prefix sums via DPP (unconditional adds) ----
    float sex = dex, sey = dey, sez = dez;
    float sox = dox, soy = doy, soz = doz;
    #define SUM_ROUND(CTRL, RM)                                              \
    do {                                                                     \
        sex += dpp_mov<CTRL, RM>(sex); sey += dpp_mov<CTRL, RM>(sey);        \
        sez += dpp_mov<CTRL, RM>(sez);                                       \
        sox += dpp_mov<CTRL, RM>(sox); soy += dpp_mov<CTRL, RM>(soy);        \
        soz += dpp_mov<CTRL, RM>(soz);                                       \
    } while (0)
    SUM_ROUND(0x111, 0xF);
    SUM_ROUND(0x112, 0xF);
    SUM_ROUND(0x114, 0xF);
    SUM_ROUND(0x118, 0xF);
    SUM_ROUND(0x142, 0xA);   // rows 1,3 add lower-row total; rows 0,2 add 0
    SUM_ROUND(0x143, 0xC);   // rows 2,3 add rows0-1 total; rows 0,1 add 0
    #undef SUM_ROUND

    // final[2l+3] = pos0[1] + Se ; final[2l+4] = pos0[2] + So
    const float p1x = sa[3], p1y = sa[4], p1z = sa[5];
    const float p2x = sa[6], p2y = sa[7], p2z = sa[8];
    const float fex = p1x + sex, fey = p1y + sey, fez = p1z + sez;
    const float fox = p2x + sox, foy = p2y + soy, foz = p2z + soz;

    {
        float* op = &sout[6*lane + 9];
        op[0] = fex; op[1] = fey; op[2] = fez;   // atom 2l+3
        op[3] = fox; op[4] = foy; op[5] = foz;   // atom 2l+4
    }
    if (lane < 9) sout[lane] = sa[lane];   // atoms 0..2 never move

    // ---- F = P_127 (S@63); translation from final[130] = fo@63 ----
    float tFx = 0.f, tFy = 0.f, tFz = 0.f;
    if (lane == 63) {
        float rx, ry, rz;
        qrotv(S, sa[390], sa[391], sa[392], rx, ry, rz);   // R_F·pos0[130]
        tFx = fox - rx; tFy = foy - ry; tFz = foz - rz;
        // atom 131 = F(pos0[131])
        qrotv(S, sa[393], sa[394], sa[395], rx, ry, rz);
        sout[393] = rx + tFx; sout[394] = ry + tFy; sout[395] = rz + tFz;
    }
    Q4 Fq;
    Fq.w = __shfl(S.w, 63, 64); Fq.x = __shfl(S.x, 63, 64);
    Fq.y = __shfl(S.y, 63, 64); Fq.z = __shfl(S.z, 63, 64);
    const float Ftx = __shfl(tFx, 63, 64), Fty = __shfl(tFy, 63, 64), Ftz = __shfl(tFz, 63, 64);
    const float f00 = 1.f - 2.f*(Fq.y*Fq.y + Fq.z*Fq.z);
    const float f01 = 2.f*(Fq.x*Fq.y - Fq.w*Fq.z);
    const float f02 = 2.f*(Fq.x*Fq.z + Fq.w*Fq.y);
    const float f10 = 2.f*(Fq.x*Fq.y + Fq.w*Fq.z);
    const float f11 = 1.f - 2.f*(Fq.x*Fq.x + Fq.z*Fq.z);
    const float f12 = 2.f*(Fq.y*Fq.z - Fq.w*Fq.x);
    const float f20 = 2.f*(Fq.x*Fq.z - Fq.w*Fq.y);
    const float f21 = 2.f*(Fq.y*Fq.z + Fq.w*Fq.x);
    const float f22 = 1.f - 2.f*(Fq.x*Fq.x + Fq.y*Fq.y);

    // ---- store head (99 f4, coalesced) ----
    const float4* so4 = (const float4*)sout;
    ob4[lane] = so4[lane];
    if (lane < 35) ob4[64 + lane] = so4[64 + lane];

    // ---- tail: already staged in LDS; transform in place (stride-3 float
    //      = 2 lanes/bank, free) and store coalesced ----
    #pragma unroll
    for (int r2 = 0; r2 < 6; ++r2) {
        const int i = r2 * 64 + lane;
        if (r2 < 5 || lane < 60) {       // 380 tail atoms
            const float x = st[3*i], y = st[3*i+1], z = st[3*i+2];
            st[3*i]   = f00*x + f01*y + f02*z + Ftx;
            st[3*i+1] = f10*x + f11*y + f12*z + Fty;
            st[3*i+2] = f20*x + f21*y + f22*z + Ftz;
        }
    }

    ob4[99 + lane]        = st4[lane];
    ob4[99 + 64 + lane]   = st4[64 + lane];
    ob4[99 + 128 + lane]  = st4[128 + lane];
    ob4[99 + 192 + lane]  = st4[192 + lane];
    if (lane < TAIL_F4 - 256) ob4[99 + 256 + lane] = st4[256 + lane];
}

extern "C" void kernel_launch(void* const* d_in, const int* in_sizes, int n_in,
                              void* d_out, int out_size, void* d_ws, size_t ws_size,
                              hipStream_t stream) {
    const float* theta = (const float*)d_in[0];  // input (N,K) fp32
    const float* pos0  = (const float*)d_in[1];  // pos0 (N,M,3) fp32
    float* out = (float*)d_out;                  // (N,M,3) fp32
    dihedral_w64_gld_kernel<<<NMOL, TPB, 0, stream>>>(theta, pos0, out);
}

// Round 22
// 15.710 us; speedup vs baseline: 1.0139x; 1.0139x over previous
//
#include <hip/hip_runtime.h>

// Dihedral2Coord — R20 structure (1-wave blocks, quat-only W64 DPP scan,
// E=S⊗conj(D), 2-stride translation chains, coalesced tail via LDS bounce)
// with final thinning: (1) in-place head emit into sa (drops sout buffer:
// -1.6KB LDS -> 26 blocks/CU), (2) F broadcast via readlane (SGPR) instead
// of ds_bpermute, F-translation from registers, (3) tail transform/store
// interleave so the store drain starts earlier.

#define NK 128
#define NM 512
#define NMOL 4096
#define TPB 64       // ONE wave per block, one molecule per block
#define TAIL_F4 285  // f4 indices 99..383 (atoms 132..511)

struct Q4 { float w, x, y, z; };

__device__ __forceinline__ Q4 qmul(const Q4& a, const Q4& b) {
    Q4 r;
    r.w = a.w*b.w - a.x*b.x - a.y*b.y - a.z*b.z;
    r.x = a.w*b.x + a.x*b.w + a.y*b.z - a.z*b.y;
    r.y = a.w*b.y - a.x*b.z + a.y*b.w + a.z*b.x;
    r.z = a.w*b.z + a.x*b.y - a.y*b.x + a.z*b.w;
    return r;
}

__device__ __forceinline__ void qrotv(const Q4& q, float vx, float vy, float vz,
                                      float& ox, float& oy, float& oz) {
    const float ux = q.y*vz - q.z*vy + q.w*vx;
    const float uy = q.z*vx - q.x*vz + q.w*vy;
    const float uz = q.x*vy - q.y*vx + q.w*vz;
    ox = vx + 2.f*(q.y*uz - q.z*uy);
    oy = vy + 2.f*(q.z*ux - q.x*uz);
    oz = vz + 2.f*(q.x*uy - q.y*ux);
}

// DPP: ROW_SHR:N = 0x110+N ; ROW_BCAST15 = 0x142 ; ROW_BCAST31 = 0x143.
template <int CTRL, int RMASK>
__device__ __forceinline__ float dpp_mov(float x) {
    return __int_as_float(__builtin_amdgcn_update_dpp(
        0, __float_as_int(x), CTRL, RMASK, 0xF, true));
}

__device__ __forceinline__ float readlane_f(float x, int l) {
    return __int_as_float(__builtin_amdgcn_readlane(__float_as_int(x), l));
}

// Direct global->LDS, 16B per lane (per-lane gsrc, wave-uniform lds base).
__device__ __forceinline__ void gload_lds16(const void* gsrc, void* lds) {
    __builtin_amdgcn_global_load_lds(
        (const __attribute__((address_space(1))) unsigned int*)gsrc,
        (__attribute__((address_space(3))) unsigned int*)lds, 16, 0, 0);
}

// Step-quat for step 2l+j (validated sphi/cphi formula, R10-R21; quat only)
#define BUILD_Q(j, OUT) do {                                                  \
    const float cxx = ny[(j)+1]*nz[(j)] - nz[(j)+1]*ny[(j)];                  \
    const float cxy = nz[(j)+1]*nx[(j)] - nx[(j)+1]*nz[(j)];                  \
    const float cxz = nx[(j)+1]*ny[(j)] - ny[(j)+1]*nx[(j)];                  \
    const float g   = cxx*vx[(j)+1] + cxy*vy[(j)+1] + cxz*vz[(j)+1];          \
    const float dnn = nx[(j)]*nx[(j)+1] + ny[(j)]*ny[(j)+1] + nz[(j)]*nz[(j)+1]; \
    const float r12 = rsqrtf(fmaxf(Ln[(j)]*Ln[(j)+1], 1e-30f));               \
    const float ira = rsqrtf(fmaxf(Lv[(j)+1], 1e-24f));                       \
    const float cphi = dnn*r12, sphi = g*r12*ira;                             \
    const float sth = __sinf(th[(j)]), cth = __cosf(th[(j)]);                 \
    const float c = cth*cphi - sth*sphi, s = sth*cphi + cth*sphi;             \
    const float hc = sqrtf(fmaxf(0.f, 0.5f*(1.f + c)));                       \
    const float hs = copysignf(sqrtf(fmaxf(0.f, 0.5f*(1.f - c))), s);         \
    const float hsa = hs*ira;                                                 \
    OUT.w = hc; OUT.x = vx[(j)+1]*hsa; OUT.y = vy[(j)+1]*hsa; OUT.z = vz[(j)+1]*hsa; \
} while (0)

__global__ __launch_bounds__(TPB) void dihedral_w64_final_kernel(
    const float* __restrict__ theta,  // (NMOL, NK)
    const float* __restrict__ pos0,   // (NMOL, NM, 3)
    float* __restrict__ out)          // (NMOL, NM, 3)
{
    const int lane = threadIdx.x;
    const int mol  = blockIdx.x;

    const float4* __restrict__ pb4 = (const float4*)(pos0 + (size_t)mol * (NM*3));
    float4*       __restrict__ ob4 = (float4*)(out  + (size_t)mol * (NM*3));

    __shared__ __align__(16) float sa[400];          // pos0 atoms 0..131 -> finals (in place)
    __shared__ __align__(16) float st[TAIL_F4 * 4];  // tail f4s (atoms 132..511)
    float4* sa4 = (float4*)sa;
    float4* st4 = (float4*)st;

    // ---- theta (register) + ALL staging as direct global->LDS DMA ----
    const float2 th2 = ((const float2*)(theta + (size_t)mol * NK))[lane];
    gload_lds16(pb4 + lane, sa4);                                    // head 0..63
    if (lane < 35) gload_lds16(pb4 + 64 + lane, sa4 + 64);           // head 64..98
    gload_lds16(pb4 +  99 + lane, st4);                              // tail rows
    gload_lds16(pb4 + 163 + lane, st4 + 64);
    gload_lds16(pb4 + 227 + lane, st4 + 128);
    gload_lds16(pb4 + 291 + lane, st4 + 192);
    if (lane < TAIL_F4 - 256) gload_lds16(pb4 + 355 + lane, st4 + 256);

    asm volatile("s_waitcnt vmcnt(0)" ::: "memory");
    __builtin_amdgcn_sched_barrier(0);

    // lane l: atoms 2l..2l+4 (15 floats)
    float A[16];
    {
        const float2* ap2 = (const float2*)&sa[lane * 6];
        #pragma unroll
        for (int i = 0; i < 7; ++i) { const float2 v = ap2[i]; A[2*i] = v.x; A[2*i+1] = v.y; }
        A[14] = sa[lane * 6 + 14];
    }

    // bonds / normals for the 2 steps
    float vx[4], vy[4], vz[4];
    #pragma unroll
    for (int i = 0; i < 4; ++i) {
        vx[i] = A[3*i+3] - A[3*i];
        vy[i] = A[3*i+4] - A[3*i+1];
        vz[i] = A[3*i+5] - A[3*i+2];
    }
    float nx[3], ny[3], nz[3], Ln[3];
    #pragma unroll
    for (int i = 0; i < 3; ++i) {
        nx[i] = vy[i]*vz[i+1] - vz[i]*vy[i+1];
        ny[i] = vz[i]*vx[i+1] - vx[i]*vz[i+1];
        nz[i] = vx[i]*vy[i+1] - vy[i]*vx[i+1];
        Ln[i] = nx[i]*nx[i] + ny[i]*ny[i] + nz[i]*nz[i];
    }
    float Lv[3];
    #pragma unroll
    for (int i = 1; i < 3; ++i) Lv[i] = vx[i]*vx[i] + vy[i]*vy[i] + vz[i]*vz[i];
    const float th[2] = {th2.x, th2.y};

    // ---- build 2 step quats; D = q0⊗q1 ----
    Q4 q0, q1;
    BUILD_Q(0, q0); BUILD_Q(1, q1);
    const Q4 D = qmul(q0, q1);
    Q4 S = D;

    // ---- 6-round W64 inclusive quat scan via DPP ----
    const int rowi = lane & 15;
    #define QSCAN_ROUND(CTRL, COND)                                          \
    do {                                                                     \
        Q4 Qp;                                                               \
        Qp.w = dpp_mov<CTRL, 0xF>(S.w); Qp.x = dpp_mov<CTRL, 0xF>(S.x);      \
        Qp.y = dpp_mov<CTRL, 0xF>(S.y); Qp.z = dpp_mov<CTRL, 0xF>(S.z);      \
        if (COND) S = qmul(Qp, S);                                           \
    } while (0)
    QSCAN_ROUND(0x111, rowi >= 1);
    QSCAN_ROUND(0x112, rowi >= 2);
    QSCAN_ROUND(0x114, rowi >= 4);
    QSCAN_ROUND(0x118, rowi >= 8);
    QSCAN_ROUND(0x142, (lane & 16) != 0);   // rows 1,3: prepend lower-row total
    QSCAN_ROUND(0x143, (lane & 32) != 0);   // rows 2,3: prepend rows0-1 total
    #undef QSCAN_ROUND

    // exclusive prefix: E = S ⊗ conj(D)  (unit quats; lane0 -> identity)
    Q4 Dc; Dc.w = D.w; Dc.x = -D.x; Dc.y = -D.y; Dc.z = -D.z;
    const Q4 E  = qmul(S, Dc);
    const Q4 Pe = qmul(E, q0);          // R(P_{2l});  R(P_{2l+1}) = S

    // ---- d = R(P_k)·(pos0[k+3]-pos0[k+1]) ----
    float dex, dey, dez, dox, doy, doz;
    qrotv(Pe, A[9]-A[3],  A[10]-A[4], A[11]-A[5], dex, dey, dez);
    qrotv(S,  A[12]-A[6], A[13]-A[7], A[14]-A[8], dox, doy, doz);

    // ---- two float3 inclusive prefix sums via DPP (unconditional adds) ----
    float sex = dex, sey = dey, sez = dez;
    float sox = dox, soy = doy, soz = doz;
    #define SUM_ROUND(CTRL, RM)                                              \
    do {                                                                     \
        sex += dpp_mov<CTRL, RM>(sex); sey += dpp_mov<CTRL, RM>(sey);        \
        sez += dpp_mov<CTRL, RM>(sez);                                       \
        sox += dpp_mov<CTRL, RM>(sox); soy += dpp_mov<CTRL, RM>(soy);        \
        soz += dpp_mov<CTRL, RM>(soz);                                       \
    } while (0)
    SUM_ROUND(0x111, 0xF);
    SUM_ROUND(0x112, 0xF);
    SUM_ROUND(0x114, 0xF);
    SUM_ROUND(0x118, 0xF);
    SUM_ROUND(0x142, 0xA);   // rows 1,3 add lower-row total; rows 0,2 add 0
    SUM_ROUND(0x143, 0xC);   // rows 2,3 add rows0-1 total; rows 0,1 add 0
    #undef SUM_ROUND

    // final[2l+3] = pos0[1] + Se ; final[2l+4] = pos0[2] + So
    const float p1x = sa[3], p1y = sa[4], p1z = sa[5];
    const float p2x = sa[6], p2y = sa[7], p2z = sa[8];
    const float fex = p1x + sex, fey = p1y + sey, fez = p1z + sez;
    const float fox = p2x + sox, foy = p2y + soy, foz = p2z + soz;

    // ---- F = P_127 (S@63); translation from final[130] = fo@63 and
    //      pos0[130] = A[12..14]@63 (all in registers; every lane computes,
    //      lane 63's value is broadcast) ----
    float rfx, rfy, rfz;
    qrotv(S, A[12], A[13], A[14], rfx, rfy, rfz);
    const float tFx_l = fox - rfx, tFy_l = foy - rfy, tFz_l = foz - rfz;
    Q4 Fq;
    Fq.w = readlane_f(S.w, 63); Fq.x = readlane_f(S.x, 63);
    Fq.y = readlane_f(S.y, 63); Fq.z = readlane_f(S.z, 63);
    const float Ftx = readlane_f(tFx_l, 63);
    const float Fty = readlane_f(tFy_l, 63);
    const float Ftz = readlane_f(tFz_l, 63);

    // ---- in-place head emit: sa[6l+9..6l+14] = {final[2l+3], final[2l+4]}
    //      (all lanes' A/p1/p2 reads above precede these writes in wave
    //       program order; atoms 0..2 (sa[0..8]) and pos0[131] (sa[393..395])
    //       are never overwritten) ----
    {
        float* op = &sa[6*lane + 9];
        op[0] = fex; op[1] = fey; op[2] = fez;
        op[3] = fox; op[4] = foy; op[5] = foz;
    }
    // atom 131 = F(pos0[131]) — any one lane; F is uniform now
    if (lane == 0) {
        float bx, by, bz;
        qrotv(Fq, sa[393], sa[394], sa[395], bx, by, bz);
        sa[393] = bx + Ftx; sa[394] = by + Fty; sa[395] = bz + Ftz;
    }

    const float f00 = 1.f - 2.f*(Fq.y*Fq.y + Fq.z*Fq.z);
    const float f01 = 2.f*(Fq.x*Fq.y - Fq.w*Fq.z);
    const float f02 = 2.f*(Fq.x*Fq.z + Fq.w*Fq.y);
    const float f10 = 2.f*(Fq.x*Fq.y + Fq.w*Fq.z);
    const float f11 = 1.f - 2.f*(Fq.x*Fq.x + Fq.z*Fq.z);
    const float f12 = 2.f*(Fq.y*Fq.z - Fq.w*Fq.x);
    const float f20 = 2.f*(Fq.x*Fq.z - Fq.w*Fq.y);
    const float f21 = 2.f*(Fq.y*Fq.z + Fq.w*Fq.x);
    const float f22 = 1.f - 2.f*(Fq.x*Fq.x + Fq.y*Fq.y);

    // ---- store head (99 f4, coalesced, straight from sa) ----
    ob4[lane] = sa4[lane];
    if (lane < 35) ob4[64 + lane] = sa4[64 + lane];

    // ---- tail: transform in place, stores interleaved so the drain starts
    //      early.  TR(r): atoms r*64+lane; ST(r): f4 row r (needs atoms
    //      < 256(r+1)/3 transformed).  Order: T0 T1 S0 T2 S1 T3 S2 T4 T5 S3 S4.
    #define TR(r2)                                                            \
    do {                                                                      \
        const int i = (r2) * 64 + lane;                                       \
        if ((r2) < 5 || lane < 60) {                                          \
            const float x = st[3*i], y = st[3*i+1], z = st[3*i+2];            \
            st[3*i]   = f00*x + f01*y + f02*z + Ftx;                          \
            st[3*i+1] = f10*x + f11*y + f12*z + Fty;                          \
            st[3*i+2] = f20*x + f21*y + f22*z + Ftz;                          \
        }                                                                     \
    } while (0)
    TR(0); TR(1);
    ob4[99 + lane]       = st4[lane];
    TR(2);
    ob4[99 + 64 + lane]  = st4[64 + lane];
    TR(3);
    ob4[99 + 128 + lane] = st4[128 + lane];
    TR(4); TR(5);
    ob4[99 + 192 + lane] = st4[192 + lane];
    if (lane < TAIL_F4 - 256) ob4[99 + 256 + lane] = st4[256 + lane];
    #undef TR
}

extern "C" void kernel_launch(void* const* d_in, const int* in_sizes, int n_in,
                              void* d_out, int out_size, void* d_ws, size_t ws_size,
                              hipStream_t stream) {
    const float* theta = (const float*)d_in[0];  // input (N,K) fp32
    const float* pos0  = (const float*)d_in[1];  // pos0 (N,M,3) fp32
    float* out = (float*)d_out;                  // (N,M,3) fp32
    dihedral_w64_final_kernel<<<NMOL, TPB, 0, stream>>>(theta, pos0, out);
}